// Round 8
// baseline (179.292 us; speedup 1.0000x reference)
//
#include <hip/hip_runtime.h>
#include <hip/hip_bf16.h>

#define NB 16
#define NN 512
#define ND 512
#define NH 8

using short8 = __attribute__((ext_vector_type(8))) short;
using f32x4  = __attribute__((ext_vector_type(4))) float;
using int4v  = __attribute__((ext_vector_type(4))) int;

static __device__ __forceinline__ unsigned short f2bf(float f) {
  unsigned u = __builtin_bit_cast(unsigned, f);
  unsigned r = 0x7fffu + ((u >> 16) & 1u);
  return (unsigned short)((u + r) >> 16);
}
static __device__ __forceinline__ float bf2f(unsigned short u) {
  return __builtin_bit_cast(float, (unsigned)u << 16);
}

// ---------------------------------------------------------------- kernel 0
// Transpose 4 weight mats [k][n] fp32 -> [n][k] bf16 (Wq,Wk,Wv,Wo)
__global__ __launch_bounds__(256) void wprep(
    const float* __restrict__ Wq, const float* __restrict__ Wk,
    const float* __restrict__ Wv, const float* __restrict__ Wo,
    unsigned short* __restrict__ T) {
  const float* W;
  switch (blockIdx.z) {
    case 0: W = Wq; break;
    case 1: W = Wk; break;
    case 2: W = Wv; break;
    default: W = Wo; break;
  }
  unsigned short* Wt = T + (size_t)blockIdx.z * 512 * 512;
  __shared__ float tile[64][65];
  const int t = threadIdx.x;
  const int k0 = blockIdx.x * 64, n0 = blockIdx.y * 64;
#pragma unroll
  for (int it = 0; it < 4; ++it) {
    int row = it * 16 + (t >> 4);
    int c4 = (t & 15) * 4;
    float4 v = *(const float4*)&W[(size_t)(k0 + row) * 512 + n0 + c4];
    tile[row][c4] = v.x; tile[row][c4 + 1] = v.y;
    tile[row][c4 + 2] = v.z; tile[row][c4 + 3] = v.w;
  }
  __syncthreads();
#pragma unroll
  for (int it = 0; it < 4; ++it) {
    int nr = it * 16 + (t >> 4);
    int k4 = (t & 15) * 4;
    ushort4 o;
    o.x = f2bf(tile[k4 + 0][nr]); o.y = f2bf(tile[k4 + 1][nr]);
    o.z = f2bf(tile[k4 + 2][nr]); o.w = f2bf(tile[k4 + 3][nr]);
    *(ushort4*)&Wt[(size_t)(n0 + nr) * 512 + k0 + k4] = o;
  }
}

// ---------------------------------------------------------------- kernel 1
// QKV projection: X[8192x512]fp32 @ Wt^T + b -> bf16, scattered to
// q_ws/k_ws [B,H,N,64], vt_ws [B,H,64,N]
__global__ __launch_bounds__(256) void qkv_gemm(
    const float* __restrict__ Xq, const float* __restrict__ Xk,
    const float* __restrict__ Xv, const unsigned short* __restrict__ Wt,
    const float* __restrict__ bq, const float* __restrict__ bk,
    const float* __restrict__ bv, unsigned short* __restrict__ q_ws,
    unsigned short* __restrict__ k_ws, unsigned short* __restrict__ vt_ws) {
  const int zi = blockIdx.z;
  const float* X = (zi == 0) ? Xq : (zi == 1) ? Xk : Xv;
  const unsigned short* Wz = Wt + (size_t)zi * 512 * 512;
  const float* bias = (zi == 0) ? bq : (zi == 1) ? bk : bv;
  const int m0 = blockIdx.x * 128, n0 = blockIdx.y * 128;
  __shared__ unsigned short Al[2][128][40];
  __shared__ unsigned short Bl[2][128][40];
  const int t = threadIdx.x;
  const int w = t >> 6, l = t & 63;
  const int lr = l & 15, lg = l >> 4;
  const int wr = (w >> 1) * 64, wc = (w & 1) * 64;
  f32x4 acc[4][4] = {};
  for (int kk = 0; kk < 512; kk += 64) {
    __syncthreads();
    {
      const int colk = (t & 15) * 4;
      const int kc = colk >> 5, kin = colk & 31;
#pragma unroll
      for (int p = 0; p < 8; ++p) {
        int row = p * 16 + (t >> 4);
        float4 v = *(const float4*)&X[(size_t)(m0 + row) * 512 + kk + colk];
        ushort4 o;
        o.x = f2bf(v.x); o.y = f2bf(v.y); o.z = f2bf(v.z); o.w = f2bf(v.w);
        *(ushort4*)&Al[kc][row][kin] = o;
      }
      const int colk8 = (t & 7) * 8;
      const int kc2 = colk8 >> 5, kin2 = colk8 & 31;
#pragma unroll
      for (int p = 0; p < 4; ++p) {
        int row = p * 32 + (t >> 3);
        short8 v = *(const short8*)&Wz[(size_t)(n0 + row) * 512 + kk + colk8];
        *(short8*)&Bl[kc2][row][kin2] = v;
      }
    }
    __syncthreads();
#pragma unroll
    for (int kc = 0; kc < 2; ++kc) {
      short8 a[4], b[4];
      const int lk = lg * 8;
#pragma unroll
      for (int i = 0; i < 4; ++i) a[i] = *(const short8*)&Al[kc][wr + i * 16 + lr][lk];
#pragma unroll
      for (int i = 0; i < 4; ++i) b[i] = *(const short8*)&Bl[kc][wc + i * 16 + lr][lk];
#pragma unroll
      for (int i = 0; i < 4; ++i)
#pragma unroll
        for (int j = 0; j < 4; ++j)
          acc[i][j] = __builtin_amdgcn_mfma_f32_16x16x32_bf16(a[i], b[j], acc[i][j], 0, 0, 0);
    }
  }
#pragma unroll
  for (int j = 0; j < 4; ++j) {
    const int col = n0 + wc + j * 16 + lr;
    const float bb = bias[col];
    const int hh = col >> 6, dv = col & 63;
#pragma unroll
    for (int i = 0; i < 4; ++i) {
      const int mbase = m0 + wr + i * 16 + lg * 4;
      const int b_ = mbase >> 9, nt = mbase & 511;
      if (zi == 2) {
        ushort4 o;
        o.x = f2bf(acc[i][j][0] + bb); o.y = f2bf(acc[i][j][1] + bb);
        o.z = f2bf(acc[i][j][2] + bb); o.w = f2bf(acc[i][j][3] + bb);
        *(ushort4*)&vt_ws[((size_t)(b_ * NH + hh) * 64 + dv) * 512 + nt] = o;
      } else {
        unsigned short* dst = (zi == 0) ? q_ws : k_ws;
#pragma unroll
        for (int r = 0; r < 4; ++r)
          dst[((size_t)(b_ * NH + hh) * 512 + nt + r) * 64 + dv] = f2bf(acc[i][j][r] + bb);
      }
    }
  }
}

// ---------------------------------------------------------------- kernel 2
// Attention v8 — wave-independent, zero-LDS, zero-barrier:
//   1 wave = 16 q-rows x ALL 512 keys of one bh. Row reductions are pure
//   intra-wave shfl (swapped QK^T puts a row across 4 lanes). P kept in
//   registers as packed bf16 (32 chunks x 2 u32 = 64 VGPR, static idx).
//   PV A-fragments built in-register via 8 shfl + 4 selects per window.
//   16 independent chains/CU (4 blk x 4 waves, no barriers) for TLP;
//   grouped loads for MLP. Wave->tile map keeps each bh on one XCD.
__global__ __launch_bounds__(256, 4) void attn_kernel(
    const unsigned short* __restrict__ q_ws, const unsigned short* __restrict__ k_ws,
    const unsigned short* __restrict__ vt_ws, const float* __restrict__ box,
    const float* __restrict__ Ext, unsigned short* __restrict__ hidden) {
  const int t = threadIdx.x;
  const int w = t >> 6, l = t & 63;
  const int lr = l & 15, lg = l >> 4;
  const int tile = blockIdx.x * 4 + w;
  const int bh = tile & 127;        // same bh -> same XCD (blk = bh/4 + 32k)
  const int q0 = (tile >> 7) * 16;
  const int b = bh >> 3, h = bh & 7;

  const unsigned short* Qp = q_ws + (size_t)bh * 512 * 64;
  const unsigned short* Kp = k_ws + (size_t)bh * 512 * 64;
  const unsigned short* Vt = vt_ws + (size_t)bh * 64 * 512;
  const float* boxp = box + ((size_t)bh * 512 + q0) * 512;
  const float* Ep = Ext + ((size_t)bh * 512 + q0) * 512;

  // Q fragments (B operand), q-col = lr
  short8 qf0 = *(const short8*)&Qp[(size_t)(q0 + lr) * 64 + lg * 8];
  short8 qf1 = *(const short8*)&Qp[(size_t)(q0 + lr) * 64 + 32 + lg * 8];

  // P packed bf16: chunk c (16 keys), lane holds keys c*16+lg*4+[0..3]
  unsigned Ppk[32][2];

  // ---- pass1: e1 = clip(box)*exp(att/8), packed to regs; row sum ----
  float s1 = 0.f;
#pragma unroll
  for (int g = 0; g < 16; ++g) {
    short8 kf[2][2];
    f32x4 bx[2];
#pragma unroll
    for (int u = 0; u < 2; ++u) {
      const int c = g * 2 + u;
      const int krow = c * 16 + lr;
      kf[u][0] = *(const short8*)&Kp[(size_t)krow * 64 + lg * 8];
      kf[u][1] = *(const short8*)&Kp[(size_t)krow * 64 + 32 + lg * 8];
      bx[u] = *(const f32x4*)&boxp[(size_t)lr * 512 + c * 16 + lg * 4];
    }
#pragma unroll
    for (int u = 0; u < 2; ++u) {
      const int c = g * 2 + u;
      f32x4 a = {0.f, 0.f, 0.f, 0.f};
      a = __builtin_amdgcn_mfma_f32_16x16x32_bf16(kf[u][0], qf0, a, 0, 0, 0);
      a = __builtin_amdgcn_mfma_f32_16x16x32_bf16(kf[u][1], qf1, a, 0, 0, 0);
      float e0 = fmaxf(bx[u][0], 1e-6f) * __expf(a[0] * 0.125f);
      float e1 = fmaxf(bx[u][1], 1e-6f) * __expf(a[1] * 0.125f);
      float e2 = fmaxf(bx[u][2], 1e-6f) * __expf(a[2] * 0.125f);
      float e3 = fmaxf(bx[u][3], 1e-6f) * __expf(a[3] * 0.125f);
      s1 += (e0 + e1) + (e2 + e3);
      Ppk[c][0] = ((unsigned)f2bf(e1) << 16) | f2bf(e0);
      Ppk[c][1] = ((unsigned)f2bf(e3) << 16) | f2bf(e2);
    }
  }
  s1 += __shfl_xor(s1, 16);
  s1 += __shfl_xor(s1, 32);
  const float l1i = 1.0f / s1;  // row lr sum (wave covers all 512 keys)

  // ---- pass2: P = exp(e1*l1i + Ext), packed in place; row sum ----
  float s2 = 0.f;
#pragma unroll
  for (int g = 0; g < 8; ++g) {
    f32x4 ex[4];
#pragma unroll
    for (int u = 0; u < 4; ++u)
      ex[u] = *(const f32x4*)&Ep[(size_t)lr * 512 + (g * 4 + u) * 16 + lg * 4];
#pragma unroll
    for (int u = 0; u < 4; ++u) {
      const int c = g * 4 + u;
      float p0 = __expf(bf2f((unsigned short)(Ppk[c][0] & 0xffff)) * l1i + ex[u][0]);
      float p1 = __expf(bf2f((unsigned short)(Ppk[c][0] >> 16)) * l1i + ex[u][1]);
      float p2 = __expf(bf2f((unsigned short)(Ppk[c][1] & 0xffff)) * l1i + ex[u][2]);
      float p3 = __expf(bf2f((unsigned short)(Ppk[c][1] >> 16)) * l1i + ex[u][3]);
      s2 += (p0 + p1) + (p2 + p3);
      Ppk[c][0] = ((unsigned)f2bf(p1) << 16) | f2bf(p0);
      Ppk[c][1] = ((unsigned)f2bf(p3) << 16) | f2bf(p2);
    }
  }
  s2 += __shfl_xor(s2, 16);
  s2 += __shfl_xor(s2, 32);

  // 1/l2 for this thread's OUTPUT rows (q = lg*4+r): fetch from lane lg*4+r
  float l2v[4];
#pragma unroll
  for (int r = 0; r < 4; ++r) l2v[r] = 1.0f / __shfl(s2, lg * 4 + r);

  // ---- PV: repack P windows in-register (shfl) + MFMA over 512 keys ----
  // pa for window kc: keys kc*32+lg*8+[0..7] of row lr.
  //   source chunk c = 2kc+(lg>>1), pair j = m&1, source lane:
  //   src0 = 2*(lg&1)*16+lr (m=0,1), src1 = src0+16 (m=2,3)
  const int src0 = (2 * (lg & 1)) * 16 + lr;
  const int src1 = src0 + 16;
  const bool hi = ((lg >> 1) & 1) != 0;
  f32x4 o4[4] = {};
#pragma unroll
  for (int kc = 0; kc < 16; ++kc) {
    short8 vf[4];
#pragma unroll
    for (int c2 = 0; c2 < 4; ++c2)
      vf[c2] = *(const short8*)&Vt[(size_t)(c2 * 16 + lr) * 512 + kc * 32 + lg * 8];
    const int a0 = __shfl((int)Ppk[2 * kc][0], src0);
    const int b0 = __shfl((int)Ppk[2 * kc + 1][0], src0);
    const int a1 = __shfl((int)Ppk[2 * kc][1], src0);
    const int b1 = __shfl((int)Ppk[2 * kc + 1][1], src0);
    const int a2 = __shfl((int)Ppk[2 * kc][0], src1);
    const int b2 = __shfl((int)Ppk[2 * kc + 1][0], src1);
    const int a3 = __shfl((int)Ppk[2 * kc][1], src1);
    const int b3 = __shfl((int)Ppk[2 * kc + 1][1], src1);
    int4v pu;
    pu[0] = hi ? b0 : a0;
    pu[1] = hi ? b1 : a1;
    pu[2] = hi ? b2 : a2;
    pu[3] = hi ? b3 : a3;
    short8 pa = __builtin_bit_cast(short8, pu);
#pragma unroll
    for (int c2 = 0; c2 < 4; ++c2)
      o4[c2] = __builtin_amdgcn_mfma_f32_16x16x32_bf16(pa, vf[c2], o4[c2], 0, 0, 0);
  }
  // ---- scale + store (rows q0+lg*4+r, cols h*64+c2*16+lr) ----
#pragma unroll
  for (int c2 = 0; c2 < 4; ++c2)
#pragma unroll
    for (int r = 0; r < 4; ++r)
      hidden[(size_t)(b * 512 + q0 + lg * 4 + r) * 512 + h * 64 + c2 * 16 + lr] =
          f2bf(o4[c2][r] * l2v[r]);
}

// ---------------------------------------------------------------- kernel 3
// out = hidden[8192x512]bf16 @ WoT + bo  (fp32 out)
__global__ __launch_bounds__(256) void out_gemm(
    const unsigned short* __restrict__ hidden, const unsigned short* __restrict__ WoT,
    const float* __restrict__ bo, float* __restrict__ out) {
  const int m0 = blockIdx.x * 128, n0 = blockIdx.y * 128;
  __shared__ unsigned short Al[2][128][40];
  __shared__ unsigned short Bl[2][128][40];
  const int t = threadIdx.x;
  const int w = t >> 6, l = t & 63;
  const int lr = l & 15, lg = l >> 4;
  const int wr = (w >> 1) * 64, wc = (w & 1) * 64;
  f32x4 acc[4][4] = {};
  for (int kk = 0; kk < 512; kk += 64) {
    __syncthreads();
    {
      const int colk8 = (t & 7) * 8;
      const int kc2 = colk8 >> 5, kin2 = colk8 & 31;
#pragma unroll
      for (int p = 0; p < 4; ++p) {
        int row = p * 32 + (t >> 3);
        short8 v = *(const short8*)&hidden[(size_t)(m0 + row) * 512 + kk + colk8];
        *(short8*)&Al[kc2][row][kin2] = v;
      }
#pragma unroll
      for (int p = 0; p < 4; ++p) {
        int row = p * 32 + (t >> 3);
        short8 v = *(const short8*)&WoT[(size_t)(n0 + row) * 512 + kk + colk8];
        *(short8*)&Bl[kc2][row][kin2] = v;
      }
    }
    __syncthreads();
#pragma unroll
    for (int kc = 0; kc < 2; ++kc) {
      short8 a[4], b[4];
      const int lk = lg * 8;
#pragma unroll
      for (int i = 0; i < 4; ++i) a[i] = *(const short8*)&Al[kc][wr + i * 16 + lr][lk];
#pragma unroll
      for (int i = 0; i < 4; ++i) b[i] = *(const short8*)&Bl[kc][wc + i * 16 + lr][lk];
#pragma unroll
      for (int i = 0; i < 4; ++i)
#pragma unroll
        for (int j = 0; j < 4; ++j)
          acc[i][j] = __builtin_amdgcn_mfma_f32_16x16x32_bf16(a[i], b[j], acc[i][j], 0, 0, 0);
    }
  }
#pragma unroll
  for (int j = 0; j < 4; ++j) {
    const int col = n0 + wc + j * 16 + lr;
    const float bb = bo[col];
#pragma unroll
    for (int i = 0; i < 4; ++i)
#pragma unroll
      for (int r = 0; r < 4; ++r)
        out[(size_t)(m0 + wr + i * 16 + lg * 4 + r) * 512 + col] = acc[i][j][r] + bb;
  }
}

// ---------------------------------------------------------------- launch
extern "C" void kernel_launch(void* const* d_in, const int* in_sizes, int n_in,
                              void* d_out, int out_size, void* d_ws, size_t ws_size,
                              hipStream_t stream) {
  const float* queries = (const float*)d_in[0];
  const float* keys = (const float*)d_in[1];
  const float* values = (const float*)d_in[2];
  const float* box = (const float*)d_in[3];
  const float* ext = (const float*)d_in[4];
  const float* Wq = (const float*)d_in[5];
  const float* bq = (const float*)d_in[6];
  const float* Wk = (const float*)d_in[7];
  const float* bk = (const float*)d_in[8];
  const float* Wv = (const float*)d_in[9];
  const float* bv = (const float*)d_in[10];
  const float* Wo = (const float*)d_in[11];
  const float* bo = (const float*)d_in[12];
  float* out = (float*)d_out;

  char* ws = (char*)d_ws;
  unsigned short* q_ws = (unsigned short*)(ws);
  unsigned short* k_ws = (unsigned short*)(ws + 8u * 1024 * 1024);
  unsigned short* vt_ws = (unsigned short*)(ws + 16u * 1024 * 1024);
  unsigned short* hidden = (unsigned short*)(ws + 24u * 1024 * 1024);
  unsigned short* wt = (unsigned short*)(ws + 32u * 1024 * 1024);  // 4 x 512KB

  wprep<<<dim3(8, 8, 4), 256, 0, stream>>>(Wq, Wk, Wv, Wo, wt);
  qkv_gemm<<<dim3(64, 4, 3), 256, 0, stream>>>(queries, keys, values, wt, bq, bk, bv,
                                               q_ws, k_ws, vt_ws);
  attn_kernel<<<dim3(1024), 256, 0, stream>>>(q_ws, k_ws, vt_ws, box, ext, hidden);
  out_gemm<<<dim3(64, 4), 256, 0, stream>>>(hidden, wt + 3u * 512 * 512, bo, out);
}